// Round 5
// baseline (180.775 us; speedup 1.0000x reference)
//
#include <hip/hip_runtime.h>
#include <math.h>

// Problem constants (from reference setup_inputs)
#define BB 32
#define TT 2048
#define HH 1024

// Native vector type for nontemporal builtins (HIP's float4 is a struct,
// which __builtin_nontemporal_load rejects).
typedef float f32x4 __attribute__((ext_vector_type(4)));

// Kernel 1: v[b,h] = sum_o dec[b,o] * W[o,h]   (v = dec @ W)
// grid (HH/64, BB/2) = (16,16); block 256 = 4 waves. Also zeroes the per-b
// completion counters used by the fused energy+softmax kernel (kernel-boundary
// release/acquire makes the zeros visible to the next dispatch).
__global__ __launch_bounds__(256)
void proj_vec_kernel(const float* __restrict__ dec,
                     const float* __restrict__ W,
                     float* __restrict__ v,
                     int* __restrict__ cnt) {
    const int tid  = threadIdx.x;
    const int lane = tid & 63;
    const int wave = tid >> 6;            // o-quarter
    const int h0   = blockIdx.x * 64;
    const int b0   = blockIdx.y * 2;

    if (blockIdx.x == 0 && blockIdx.y == 0 && tid < BB) cnt[tid] = 0;

    __shared__ float sdec[2][HH];         // 8 KB
    {
        const float4* src = reinterpret_cast<const float4*>(dec + (size_t)b0 * HH);
        float4* dst = reinterpret_cast<float4*>(&sdec[0][0]);
        dst[tid]       = src[tid];
        dst[tid + 256] = src[tid + 256];
    }
    __syncthreads();

    const int o0 = wave * 256;
    const float* sd0 = &sdec[0][o0];
    const float* sd1 = &sdec[1][o0];
    const float* Wcol = W + (size_t)o0 * HH + h0 + lane;

    float a0 = 0.f, a1 = 0.f;
#pragma unroll 4
    for (int oo = 0; oo < 256; oo += 4) {
        float4 d0 = *reinterpret_cast<const float4*>(sd0 + oo);  // LDS broadcast
        float4 d1 = *reinterpret_cast<const float4*>(sd1 + oo);
        float w0 = Wcol[(size_t)(oo + 0) * HH];
        float w1 = Wcol[(size_t)(oo + 1) * HH];
        float w2 = Wcol[(size_t)(oo + 2) * HH];
        float w3 = Wcol[(size_t)(oo + 3) * HH];
        a0 += d0.x * w0 + d0.y * w1 + d0.z * w2 + d0.w * w3;
        a1 += d1.x * w0 + d1.y * w1 + d1.z * w2 + d1.w * w3;
    }

    __shared__ float red[4][2][64];
    red[wave][0][lane] = a0;
    red[wave][1][lane] = a1;
    __syncthreads();
    if (tid < 128) {
        const int b = tid >> 6;
        v[(size_t)(b0 + b) * HH + h0 + lane] =
            (red[0][b][lane] + red[1][b][lane]) +
            (red[2][b][lane] + red[3][b][lane]);
    }
}

// Kernel 2 (fused): energy[b,t] = enc[b,t,:] . v[b,:]  +  softmax over t.
// grid (64, BB); block 256 = 4 waves; each wave streams 8 rows (32 KB).
// Energies are written with agent-scope coherent stores; the 64th block of
// each b (by atomicAdd arrival) performs the softmax for that b. Deadlock-free
// (no spinning), deterministic output (all energies visible before any read).
__global__ __launch_bounds__(256)
void energy_softmax_kernel(const float* __restrict__ enc,
                           const float* __restrict__ v,
                           float* __restrict__ energy,
                           int* __restrict__ cnt,
                           float* __restrict__ out) {
    const int wave = threadIdx.x >> 6;
    const int lane = threadIdx.x & 63;
    const int b    = blockIdx.y;
    const int wid  = blockIdx.x * 4 + wave;      // 0..255 within this b
    const int t0   = wid * 8;                    // first of 8 rows

    const float4* v4 = reinterpret_cast<const float4*>(v + b * HH);
    const float4 w0 = v4[0 * 64 + lane];
    const float4 w1 = v4[1 * 64 + lane];
    const float4 w2 = v4[2 * 64 + lane];
    const float4 w3 = v4[3 * 64 + lane];

    const f32x4* ebase =
        reinterpret_cast<const f32x4*>(enc + ((size_t)b * TT + t0) * HH);

    float racc[8];
#pragma unroll
    for (int r = 0; r < 8; ++r) {
        const f32x4* e4 = ebase + (size_t)r * (HH / 4);
        f32x4 e0 = __builtin_nontemporal_load(e4 + 0 * 64 + lane);
        f32x4 e1 = __builtin_nontemporal_load(e4 + 1 * 64 + lane);
        f32x4 e2 = __builtin_nontemporal_load(e4 + 2 * 64 + lane);
        f32x4 e3 = __builtin_nontemporal_load(e4 + 3 * 64 + lane);
        // 4 independent partial chains -> short dependency depth
        float p0 = e0.x * w0.x + e0.y * w0.y + e0.z * w0.z + e0.w * w0.w;
        float p1 = e1.x * w1.x + e1.y * w1.y + e1.z * w1.z + e1.w * w1.w;
        float p2 = e2.x * w2.x + e2.y * w2.y + e2.z * w2.z + e2.w * w2.w;
        float p3 = e3.x * w3.x + e3.y * w3.y + e3.z * w3.z + e3.w * w3.w;
        racc[r] = (p0 + p1) + (p2 + p3);
    }

    // 8 independent butterfly reductions (pipelined, latency hidden)
#pragma unroll
    for (int off = 32; off > 0; off >>= 1) {
#pragma unroll
        for (int r = 0; r < 8; ++r) racc[r] += __shfl_xor(racc[r], off, 64);
    }

    if (lane < 8) {
        float myv = racc[0];
#pragma unroll
        for (int r = 1; r < 8; ++r) if (lane == r) myv = racc[r];
        __hip_atomic_store(&energy[b * TT + t0 + lane], myv,
                           __ATOMIC_RELAXED, __HIP_MEMORY_SCOPE_AGENT);
    }

    // --- completion counting: last block of this b runs the softmax ---
    __shared__ int sLast;
    __syncthreads();
    if (threadIdx.x == 0) {
        __threadfence();                          // release our energy stores
        int prev = atomicAdd(&cnt[b], 1);         // device-scope by default
        sLast = (prev == 63) ? 1 : 0;
    }
    __syncthreads();
    if (!sLast) return;

    __threadfence();                              // acquire others' stores
    const int tid = threadIdx.x;
    float vals[8];
    float m = -INFINITY;
#pragma unroll
    for (int k = 0; k < 8; ++k) {
        vals[k] = __hip_atomic_load(&energy[b * TT + tid + k * 256],
                                    __ATOMIC_RELAXED, __HIP_MEMORY_SCOPE_AGENT);
        m = fmaxf(m, vals[k]);
    }
    __shared__ float redm[4];
    __shared__ float reds[4];
#pragma unroll
    for (int off = 32; off > 0; off >>= 1) m = fmaxf(m, __shfl_xor(m, off, 64));
    if ((tid & 63) == 0) redm[tid >> 6] = m;
    __syncthreads();
    m = fmaxf(fmaxf(redm[0], redm[1]), fmaxf(redm[2], redm[3]));

    float s = 0.f;
#pragma unroll
    for (int k = 0; k < 8; ++k) {
        vals[k] = __expf(vals[k] - m);
        s += vals[k];
    }
#pragma unroll
    for (int off = 32; off > 0; off >>= 1) s += __shfl_xor(s, off, 64);
    if ((tid & 63) == 0) reds[tid >> 6] = s;
    __syncthreads();
    s = reds[0] + reds[1] + reds[2] + reds[3];
    const float inv = 1.0f / s;
#pragma unroll
    for (int k = 0; k < 8; ++k) out[b * TT + tid + k * 256] = vals[k] * inv;
}

extern "C" void kernel_launch(void* const* d_in, const int* in_sizes, int n_in,
                              void* d_out, int out_size, void* d_ws, size_t ws_size,
                              hipStream_t stream) {
    const float* dec = (const float*)d_in[0];   // [B,H]
    const float* enc = (const float*)d_in[1];   // [B,T,H]
    const float* W   = (const float*)d_in[2];   // [H,H] (row = o, col = h)
    // d_in[3] (bias) is intentionally unused: it contributes a per-b constant
    // to the energies, which softmax's shift invariance cancels exactly.
    float* out = (float*)d_out;                 // [B,T,1] f32

    float* v      = (float*)d_ws;               // BB*HH floats = 128 KiB
    float* energy = v + BB * HH;                // BB*TT floats = 256 KiB
    int*   cnt    = (int*)(energy + BB * TT);   // BB ints (zeroed by proj)

    proj_vec_kernel<<<dim3(HH / 64, BB / 2), 256, 0, stream>>>(dec, W, v, cnt);
    energy_softmax_kernel<<<dim3(64, BB), 256, 0, stream>>>(enc, v, energy, cnt, out);
}

// Round 6
// 134.123 us; speedup vs baseline: 1.3478x; 1.3478x over previous
//
#include <hip/hip_runtime.h>
#include <math.h>

// Problem constants (from reference setup_inputs)
#define BB 32
#define TT 2048
#define HH 1024

// Kernel 1: v[b,h] = sum_o dec[b,o] * W[o,h]   (v = dec @ W)
// grid (HH/64, BB/2) = (16,16); block 256 = 4 waves. Also zeroes the per-b
// completion counters used by the fused energy+softmax kernel.
__global__ __launch_bounds__(256)
void proj_vec_kernel(const float* __restrict__ dec,
                     const float* __restrict__ W,
                     float* __restrict__ v,
                     int* __restrict__ cnt) {
    const int tid  = threadIdx.x;
    const int lane = tid & 63;
    const int wave = tid >> 6;            // o-quarter
    const int h0   = blockIdx.x * 64;
    const int b0   = blockIdx.y * 2;

    if (blockIdx.x == 0 && blockIdx.y == 0 && tid < BB) {
        __hip_atomic_store(&cnt[tid], 0, __ATOMIC_RELAXED,
                           __HIP_MEMORY_SCOPE_AGENT);
    }

    __shared__ float sdec[2][HH];         // 8 KB
    {
        const float4* src = reinterpret_cast<const float4*>(dec + (size_t)b0 * HH);
        float4* dst = reinterpret_cast<float4*>(&sdec[0][0]);
        dst[tid]       = src[tid];
        dst[tid + 256] = src[tid + 256];
    }
    __syncthreads();

    const int o0 = wave * 256;
    const float* sd0 = &sdec[0][o0];
    const float* sd1 = &sdec[1][o0];
    const float* Wcol = W + (size_t)o0 * HH + h0 + lane;

    float a0 = 0.f, a1 = 0.f;
#pragma unroll 4
    for (int oo = 0; oo < 256; oo += 4) {
        float4 d0 = *reinterpret_cast<const float4*>(sd0 + oo);  // LDS broadcast
        float4 d1 = *reinterpret_cast<const float4*>(sd1 + oo);
        float w0 = Wcol[(size_t)(oo + 0) * HH];
        float w1 = Wcol[(size_t)(oo + 1) * HH];
        float w2 = Wcol[(size_t)(oo + 2) * HH];
        float w3 = Wcol[(size_t)(oo + 3) * HH];
        a0 += d0.x * w0 + d0.y * w1 + d0.z * w2 + d0.w * w3;
        a1 += d1.x * w0 + d1.y * w1 + d1.z * w2 + d1.w * w3;
    }

    __shared__ float red[4][2][64];
    red[wave][0][lane] = a0;
    red[wave][1][lane] = a1;
    __syncthreads();
    if (tid < 128) {
        const int b = tid >> 6;
        v[(size_t)(b0 + b) * HH + h0 + lane] =
            (red[0][b][lane] + red[1][b][lane]) +
            (red[2][b][lane] + red[3][b][lane]);
    }
}

// Kernel 2 (fused): energy[b,t] = enc[b,t,:] . v[b,:]  +  softmax over t.
// grid (64, BB); block 256 = 4 waves; each wave streams 8 rows (32 KB),
// exactly R2's proven load/reduce structure (plain cached float4 loads).
// Energies are written with agent-scope relaxed atomic stores (they land at
// the device coherence point -> no cache flush needed anywhere). The 64th
// block of each b (by ACQ_REL atomicAdd arrival) performs the softmax.
// Deadlock-free (no spinning), deterministic values.
__global__ __launch_bounds__(256)
void energy_softmax_kernel(const float* __restrict__ enc,
                           const float* __restrict__ v,
                           float* __restrict__ energy,
                           int* __restrict__ cnt,
                           float* __restrict__ out) {
    const int wave = threadIdx.x >> 6;
    const int lane = threadIdx.x & 63;
    const int b    = blockIdx.y;
    const int wid  = blockIdx.x * 4 + wave;      // 0..255 within this b
    const int t0   = wid * 8;                    // first of 8 rows

    const float4* v4 = reinterpret_cast<const float4*>(v + b * HH);
    const float4 w0 = v4[0 * 64 + lane];
    const float4 w1 = v4[1 * 64 + lane];
    const float4 w2 = v4[2 * 64 + lane];
    const float4 w3 = v4[3 * 64 + lane];

    const float4* ebase =
        reinterpret_cast<const float4*>(enc + ((size_t)b * TT + t0) * HH);

#pragma unroll 2
    for (int r = 0; r < 8; ++r) {
        const float4* e4 = ebase + (size_t)r * (HH / 4);
        float4 e0 = e4[0 * 64 + lane];
        float4 e1 = e4[1 * 64 + lane];
        float4 e2 = e4[2 * 64 + lane];
        float4 e3 = e4[3 * 64 + lane];
        float acc = e0.x * w0.x + e0.y * w0.y + e0.z * w0.z + e0.w * w0.w;
        acc += e1.x * w1.x + e1.y * w1.y + e1.z * w1.z + e1.w * w1.w;
        acc += e2.x * w2.x + e2.y * w2.y + e2.z * w2.z + e2.w * w2.w;
        acc += e3.x * w3.x + e3.y * w3.y + e3.z * w3.z + e3.w * w3.w;
#pragma unroll
        for (int off = 32; off > 0; off >>= 1) acc += __shfl_down(acc, off, 64);
        if (lane == 0) {
            __hip_atomic_store(&energy[b * TT + t0 + r], acc,
                               __ATOMIC_RELAXED, __HIP_MEMORY_SCOPE_AGENT);
        }
    }

    // --- completion counting: last-arriving block of this b runs softmax ---
    __shared__ int sLast;
    __syncthreads();
    if (threadIdx.x == 0) {
        // RELEASE: orders our energy stores (s_waitcnt vmcnt(0)) before the
        // RMW. ACQUIRE: makes all other blocks' released stores visible to
        // this block when we turn out to be the last one. Agent scope only.
        int prev = __hip_atomic_fetch_add(&cnt[b], 1, __ATOMIC_ACQ_REL,
                                          __HIP_MEMORY_SCOPE_AGENT);
        sLast = (prev == 63) ? 1 : 0;
    }
    __syncthreads();
    if (!sLast) return;

    const int tid = threadIdx.x;
    float vals[8];
    float m = -INFINITY;
#pragma unroll
    for (int k = 0; k < 8; ++k) {
        vals[k] = __hip_atomic_load(&energy[b * TT + tid + k * 256],
                                    __ATOMIC_RELAXED, __HIP_MEMORY_SCOPE_AGENT);
        m = fmaxf(m, vals[k]);
    }
    __shared__ float redm[4];
    __shared__ float reds[4];
#pragma unroll
    for (int off = 32; off > 0; off >>= 1) m = fmaxf(m, __shfl_xor(m, off, 64));
    if ((tid & 63) == 0) redm[tid >> 6] = m;
    __syncthreads();
    m = fmaxf(fmaxf(redm[0], redm[1]), fmaxf(redm[2], redm[3]));

    float s = 0.f;
#pragma unroll
    for (int k = 0; k < 8; ++k) {
        vals[k] = __expf(vals[k] - m);
        s += vals[k];
    }
#pragma unroll
    for (int off = 32; off > 0; off >>= 1) s += __shfl_xor(s, off, 64);
    if ((tid & 63) == 0) reds[tid >> 6] = s;
    __syncthreads();
    s = reds[0] + reds[1] + reds[2] + reds[3];
    const float inv = 1.0f / s;
#pragma unroll
    for (int k = 0; k < 8; ++k) out[b * TT + tid + k * 256] = vals[k] * inv;
}

extern "C" void kernel_launch(void* const* d_in, const int* in_sizes, int n_in,
                              void* d_out, int out_size, void* d_ws, size_t ws_size,
                              hipStream_t stream) {
    const float* dec = (const float*)d_in[0];   // [B,H]
    const float* enc = (const float*)d_in[1];   // [B,T,H]
    const float* W   = (const float*)d_in[2];   // [H,H] (row = o, col = h)
    // d_in[3] (bias) is intentionally unused: it contributes a per-b constant
    // to the energies, which softmax's shift invariance cancels exactly.
    float* out = (float*)d_out;                 // [B,T,1] f32

    float* v      = (float*)d_ws;               // BB*HH floats = 128 KiB
    float* energy = v + BB * HH;                // BB*TT floats = 256 KiB
    int*   cnt    = (int*)(energy + BB * TT);   // BB ints (zeroed by proj)

    proj_vec_kernel<<<dim3(HH / 64, BB / 2), 256, 0, stream>>>(dec, W, v, cnt);
    energy_softmax_kernel<<<dim3(64, BB), 256, 0, stream>>>(enc, v, energy, cnt, out);
}

// Round 7
// 67.522 us; speedup vs baseline: 2.6773x; 1.9864x over previous
//
#include <hip/hip_runtime.h>
#include <math.h>

// Problem constants (from reference setup_inputs)
#define BB 32
#define TT 2048
#define HH 1024

// Kernel 1: v[b,h] = sum_o dec[b,o] * W[o,h]   (v = dec @ W)
// grid (HH/64, BB/2) = (16,16); block 256 = 4 waves. Also zeroes the per-b
// completion counters used by the fused energy+softmax kernel.
__global__ __launch_bounds__(256)
void proj_vec_kernel(const float* __restrict__ dec,
                     const float* __restrict__ W,
                     float* __restrict__ v,
                     int* __restrict__ cnt) {
    const int tid  = threadIdx.x;
    const int lane = tid & 63;
    const int wave = tid >> 6;            // o-quarter
    const int h0   = blockIdx.x * 64;
    const int b0   = blockIdx.y * 2;

    if (blockIdx.x == 0 && blockIdx.y == 0 && tid < BB) {
        __hip_atomic_store(&cnt[tid], 0, __ATOMIC_RELAXED,
                           __HIP_MEMORY_SCOPE_AGENT);
    }

    __shared__ float sdec[2][HH];         // 8 KB
    {
        const float4* src = reinterpret_cast<const float4*>(dec + (size_t)b0 * HH);
        float4* dst = reinterpret_cast<float4*>(&sdec[0][0]);
        dst[tid]       = src[tid];
        dst[tid + 256] = src[tid + 256];
    }
    __syncthreads();

    const int o0 = wave * 256;
    const float* sd0 = &sdec[0][o0];
    const float* sd1 = &sdec[1][o0];
    const float* Wcol = W + (size_t)o0 * HH + h0 + lane;

    float a0 = 0.f, a1 = 0.f;
#pragma unroll 4
    for (int oo = 0; oo < 256; oo += 4) {
        float4 d0 = *reinterpret_cast<const float4*>(sd0 + oo);  // LDS broadcast
        float4 d1 = *reinterpret_cast<const float4*>(sd1 + oo);
        float w0 = Wcol[(size_t)(oo + 0) * HH];
        float w1 = Wcol[(size_t)(oo + 1) * HH];
        float w2 = Wcol[(size_t)(oo + 2) * HH];
        float w3 = Wcol[(size_t)(oo + 3) * HH];
        a0 += d0.x * w0 + d0.y * w1 + d0.z * w2 + d0.w * w3;
        a1 += d1.x * w0 + d1.y * w1 + d1.z * w2 + d1.w * w3;
    }

    __shared__ float red[4][2][64];
    red[wave][0][lane] = a0;
    red[wave][1][lane] = a1;
    __syncthreads();
    if (tid < 128) {
        const int b = tid >> 6;
        v[(size_t)(b0 + b) * HH + h0 + lane] =
            (red[0][b][lane] + red[1][b][lane]) +
            (red[2][b][lane] + red[3][b][lane]);
    }
}

// Kernel 2 (fused): energy[b,t] = enc[b,t,:] . v[b,:]  +  softmax over t.
// grid (64, BB); block 256 = 4 waves; each wave streams 8 rows (32 KB),
// exactly R2's proven load/reduce structure (plain cached float4 loads).
//
// Coherence protocol (the R5/R6 poison was an L2-invalidate per block):
//  - energy written via RELAXED agent-scope atomic stores -> land at the LLC
//    coherence point directly; L2 never holds dirty energy lines.
//  - release = per-wave `s_waitcnt vmcnt(0)` + __syncthreads, then thread 0
//    does a RELAXED fetch_add. NO cache maintenance on losing blocks.
//  - acquire = ONLY the 32 winner blocks issue an agent acquire fence and
//    read energies back with agent-scope relaxed atomic loads (LLC-direct).
__global__ __launch_bounds__(256)
void energy_softmax_kernel(const float* __restrict__ enc,
                           const float* __restrict__ v,
                           float* __restrict__ energy,
                           int* __restrict__ cnt,
                           float* __restrict__ out) {
    const int wave = threadIdx.x >> 6;
    const int lane = threadIdx.x & 63;
    const int b    = blockIdx.y;
    const int wid  = blockIdx.x * 4 + wave;      // 0..255 within this b
    const int t0   = wid * 8;                    // first of 8 rows

    const float4* v4 = reinterpret_cast<const float4*>(v + b * HH);
    const float4 w0 = v4[0 * 64 + lane];
    const float4 w1 = v4[1 * 64 + lane];
    const float4 w2 = v4[2 * 64 + lane];
    const float4 w3 = v4[3 * 64 + lane];

    const float4* ebase =
        reinterpret_cast<const float4*>(enc + ((size_t)b * TT + t0) * HH);

#pragma unroll 2
    for (int r = 0; r < 8; ++r) {
        const float4* e4 = ebase + (size_t)r * (HH / 4);
        float4 e0 = e4[0 * 64 + lane];
        float4 e1 = e4[1 * 64 + lane];
        float4 e2 = e4[2 * 64 + lane];
        float4 e3 = e4[3 * 64 + lane];
        float acc = e0.x * w0.x + e0.y * w0.y + e0.z * w0.z + e0.w * w0.w;
        acc += e1.x * w1.x + e1.y * w1.y + e1.z * w1.z + e1.w * w1.w;
        acc += e2.x * w2.x + e2.y * w2.y + e2.z * w2.z + e2.w * w2.w;
        acc += e3.x * w3.x + e3.y * w3.y + e3.z * w3.z + e3.w * w3.w;
#pragma unroll
        for (int off = 32; off > 0; off >>= 1) acc += __shfl_down(acc, off, 64);
        if (lane == 0) {
            __hip_atomic_store(&energy[b * TT + t0 + r], acc,
                               __ATOMIC_RELAXED, __HIP_MEMORY_SCOPE_AGENT);
        }
    }

    // --- completion counting: last-arriving block of this b runs softmax ---
    // Manual release: every wave drains its own stores to the coherence
    // point, the block barrier collects all four waves, then one RELAXED RMW.
    asm volatile("s_waitcnt vmcnt(0)" ::: "memory");
    __shared__ int sLast;
    __syncthreads();
    if (threadIdx.x == 0) {
        int prev = __hip_atomic_fetch_add(&cnt[b], 1, __ATOMIC_RELAXED,
                                          __HIP_MEMORY_SCOPE_AGENT);
        sLast = (prev == 63) ? 1 : 0;
    }
    __syncthreads();
    if (!sLast) return;

    // Winner only (32 blocks total): acquire, then LLC-direct energy reads.
    __builtin_amdgcn_fence(__ATOMIC_ACQUIRE, "agent");
    const int tid = threadIdx.x;
    float vals[8];
    float m = -INFINITY;
#pragma unroll
    for (int k = 0; k < 8; ++k) {
        vals[k] = __hip_atomic_load(&energy[b * TT + tid + k * 256],
                                    __ATOMIC_RELAXED, __HIP_MEMORY_SCOPE_AGENT);
        m = fmaxf(m, vals[k]);
    }
    __shared__ float redm[4];
    __shared__ float reds[4];
#pragma unroll
    for (int off = 32; off > 0; off >>= 1) m = fmaxf(m, __shfl_xor(m, off, 64));
    if ((tid & 63) == 0) redm[tid >> 6] = m;
    __syncthreads();
    m = fmaxf(fmaxf(redm[0], redm[1]), fmaxf(redm[2], redm[3]));

    float s = 0.f;
#pragma unroll
    for (int k = 0; k < 8; ++k) {
        vals[k] = __expf(vals[k] - m);
        s += vals[k];
    }
#pragma unroll
    for (int off = 32; off > 0; off >>= 1) s += __shfl_xor(s, off, 64);
    if ((tid & 63) == 0) reds[tid >> 6] = s;
    __syncthreads();
    s = reds[0] + reds[1] + reds[2] + reds[3];
    const float inv = 1.0f / s;
#pragma unroll
    for (int k = 0; k < 8; ++k) out[b * TT + tid + k * 256] = vals[k] * inv;
}

extern "C" void kernel_launch(void* const* d_in, const int* in_sizes, int n_in,
                              void* d_out, int out_size, void* d_ws, size_t ws_size,
                              hipStream_t stream) {
    const float* dec = (const float*)d_in[0];   // [B,H]
    const float* enc = (const float*)d_in[1];   // [B,T,H]
    const float* W   = (const float*)d_in[2];   // [H,H] (row = o, col = h)
    // d_in[3] (bias) is intentionally unused: it contributes a per-b constant
    // to the energies, which softmax's shift invariance cancels exactly.
    float* out = (float*)d_out;                 // [B,T,1] f32

    float* v      = (float*)d_ws;               // BB*HH floats = 128 KiB
    float* energy = v + BB * HH;                // BB*TT floats = 256 KiB
    int*   cnt    = (int*)(energy + BB * TT);   // BB ints (zeroed by proj)

    proj_vec_kernel<<<dim3(HH / 64, BB / 2), 256, 0, stream>>>(dec, W, v, cnt);
    energy_softmax_kernel<<<dim3(64, BB), 256, 0, stream>>>(enc, v, energy, cnt, out);
}

// Round 8
// 58.578 us; speedup vs baseline: 3.0860x; 1.1527x over previous
//
#include <hip/hip_runtime.h>
#include <math.h>

// Problem constants (from reference setup_inputs)
#define BB 32
#define TT 2048
#define HH 1024

// Kernel 1: v[b,h] = sum_o dec[b,o] * W[o,h]   (v = dec @ W)
// grid (HH/64, BB/2) = (16,16); block 256 = 4 waves.
__global__ __launch_bounds__(256)
void proj_vec_kernel(const float* __restrict__ dec,
                     const float* __restrict__ W,
                     float* __restrict__ v) {
    const int tid  = threadIdx.x;
    const int lane = tid & 63;
    const int wave = tid >> 6;            // o-quarter
    const int h0   = blockIdx.x * 64;
    const int b0   = blockIdx.y * 2;

    __shared__ float sdec[2][HH];         // 8 KB
    {
        const float4* src = reinterpret_cast<const float4*>(dec + (size_t)b0 * HH);
        float4* dst = reinterpret_cast<float4*>(&sdec[0][0]);
        dst[tid]       = src[tid];
        dst[tid + 256] = src[tid + 256];
    }
    __syncthreads();

    const int o0 = wave * 256;
    const float* sd0 = &sdec[0][o0];
    const float* sd1 = &sdec[1][o0];
    const float* Wcol = W + (size_t)o0 * HH + h0 + lane;

    float a0 = 0.f, a1 = 0.f;
#pragma unroll 4
    for (int oo = 0; oo < 256; oo += 4) {
        float4 d0 = *reinterpret_cast<const float4*>(sd0 + oo);  // LDS broadcast
        float4 d1 = *reinterpret_cast<const float4*>(sd1 + oo);
        float w0 = Wcol[(size_t)(oo + 0) * HH];
        float w1 = Wcol[(size_t)(oo + 1) * HH];
        float w2 = Wcol[(size_t)(oo + 2) * HH];
        float w3 = Wcol[(size_t)(oo + 3) * HH];
        a0 += d0.x * w0 + d0.y * w1 + d0.z * w2 + d0.w * w3;
        a1 += d1.x * w0 + d1.y * w1 + d1.z * w2 + d1.w * w3;
    }

    __shared__ float red[4][2][64];
    red[wave][0][lane] = a0;
    red[wave][1][lane] = a1;
    __syncthreads();
    if (tid < 128) {
        const int b = tid >> 6;
        v[(size_t)(b0 + b) * HH + h0 + lane] =
            (red[0][b][lane] + red[1][b][lane]) +
            (red[2][b][lane] + red[3][b][lane]);
    }
}

// Kernel 2: energy[b,t] = enc[b,t,:] . v[b,:]
// grid (64, BB) = 2048 blocks; block 256 = 4 waves; each wave owns 8 rows.
// MLP restructure vs R2: ALL 32 float4 loads issue before any reduction
// (full unroll into racc[8]), then 8 independent butterfly chains pipelined,
// then ONE coalesced 8-lane store per wave. No atomics, no fences, no NT.
__global__ __launch_bounds__(256)
void energy_kernel(const float* __restrict__ enc,
                   const float* __restrict__ v,
                   float* __restrict__ energy) {
    const int wave = threadIdx.x >> 6;
    const int lane = threadIdx.x & 63;
    const int b    = blockIdx.y;
    const int wid  = blockIdx.x * 4 + wave;      // 0..255 within this b
    const int t0   = wid * 8;                    // first of 8 rows

    const float4* v4 = reinterpret_cast<const float4*>(v + b * HH);
    const float4 w0 = v4[0 * 64 + lane];
    const float4 w1 = v4[1 * 64 + lane];
    const float4 w2 = v4[2 * 64 + lane];
    const float4 w3 = v4[3 * 64 + lane];

    const float4* ebase =
        reinterpret_cast<const float4*>(enc + ((size_t)b * TT + t0) * HH);

    float racc[8];
#pragma unroll
    for (int r = 0; r < 8; ++r) {
        const float4* e4 = ebase + (size_t)r * (HH / 4);
        float4 e0 = e4[0 * 64 + lane];
        float4 e1 = e4[1 * 64 + lane];
        float4 e2 = e4[2 * 64 + lane];
        float4 e3 = e4[3 * 64 + lane];
        float p0 = e0.x * w0.x + e0.y * w0.y + e0.z * w0.z + e0.w * w0.w;
        float p1 = e1.x * w1.x + e1.y * w1.y + e1.z * w1.z + e1.w * w1.w;
        float p2 = e2.x * w2.x + e2.y * w2.y + e2.z * w2.z + e2.w * w2.w;
        float p3 = e3.x * w3.x + e3.y * w3.y + e3.z * w3.z + e3.w * w3.w;
        racc[r] = (p0 + p1) + (p2 + p3);
    }

    // 8 independent butterfly reductions (latency pipelined)
#pragma unroll
    for (int off = 32; off > 0; off >>= 1) {
#pragma unroll
        for (int r = 0; r < 8; ++r) racc[r] += __shfl_xor(racc[r], off, 64);
    }

    // One coalesced 32 B store per wave; static select chain (no scratch).
    if (lane < 8) {
        float myv = racc[0];
#pragma unroll
        for (int r = 1; r < 8; ++r) if (lane == r) myv = racc[r];
        energy[b * TT + t0 + lane] = myv;
    }
}

// Kernel 3: softmax over t for each b. One block (256 threads) per b.
__global__ __launch_bounds__(256)
void softmax_kernel(const float* __restrict__ energy,
                    float* __restrict__ out) {
    const int b   = blockIdx.x;
    const int tid = threadIdx.x;
    const float* e = energy + b * TT;
    float vals[8];
    float m = -INFINITY;
#pragma unroll
    for (int k = 0; k < 8; ++k) {
        vals[k] = e[tid + k * 256];
        m = fmaxf(m, vals[k]);
    }
    __shared__ float redm[4];
    __shared__ float reds[4];
#pragma unroll
    for (int off = 32; off > 0; off >>= 1) m = fmaxf(m, __shfl_xor(m, off, 64));
    if ((tid & 63) == 0) redm[tid >> 6] = m;
    __syncthreads();
    m = fmaxf(fmaxf(redm[0], redm[1]), fmaxf(redm[2], redm[3]));

    float s = 0.f;
#pragma unroll
    for (int k = 0; k < 8; ++k) {
        vals[k] = __expf(vals[k] - m);
        s += vals[k];
    }
#pragma unroll
    for (int off = 32; off > 0; off >>= 1) s += __shfl_xor(s, off, 64);
    if ((tid & 63) == 0) reds[tid >> 6] = s;
    __syncthreads();
    s = reds[0] + reds[1] + reds[2] + reds[3];
    const float inv = 1.0f / s;
#pragma unroll
    for (int k = 0; k < 8; ++k) out[b * TT + tid + k * 256] = vals[k] * inv;
}

extern "C" void kernel_launch(void* const* d_in, const int* in_sizes, int n_in,
                              void* d_out, int out_size, void* d_ws, size_t ws_size,
                              hipStream_t stream) {
    const float* dec = (const float*)d_in[0];   // [B,H]
    const float* enc = (const float*)d_in[1];   // [B,T,H]
    const float* W   = (const float*)d_in[2];   // [H,H] (row = o, col = h)
    // d_in[3] (bias) is intentionally unused: it contributes a per-b constant
    // to the energies, which softmax's shift invariance cancels exactly.
    float* out = (float*)d_out;                 // [B,T,1] f32

    float* v      = (float*)d_ws;               // BB*HH floats = 128 KiB
    float* energy = v + BB * HH;                // BB*TT floats = 256 KiB

    proj_vec_kernel<<<dim3(HH / 64, BB / 2), 256, 0, stream>>>(dec, W, v);
    energy_kernel<<<dim3(64, BB), 256, 0, stream>>>(enc, v, energy);
    softmax_kernel<<<BB, 256, 0, stream>>>(energy, out);
}